// Round 1
// baseline (3354.847 us; speedup 1.0000x reference)
//
#include <hip/hip_runtime.h>
#include <math.h>

// Problem constants
#define ALPHA_ 0.1f
#define BETA_  0.9f
#define EPS_   1e-5f
// sizes: BS=8, SD=200, SL=96, HS=64, 3HS=192, per-batch LN count = 200*96*64 = 1228800

__device__ __forceinline__ float wave_reduce_sum(float v) {
#pragma unroll
    for (int off = 32; off > 0; off >>= 1) v += __shfl_down(v, off, 64);
    return v;
}

// ---------------- LN partial sums (per-b mean/var, stage 1) ----------------
__global__ void k_ln_part(const float4* __restrict__ x4, float2* __restrict__ part) {
    const int b = blockIdx.y, jb = blockIdx.x, t = threadIdx.x;
    const size_t base = (size_t)b * 307200 + (size_t)jb * 4096;
    float s = 0.f, sq = 0.f;
#pragma unroll
    for (int k = 0; k < 16; k++) {
        float4 v = x4[base + k * 256 + t];
        s  += v.x + v.y + v.z + v.w;
        sq += v.x * v.x + v.y * v.y + v.z * v.z + v.w * v.w;
    }
    float rs = wave_reduce_sum(s);
    float rq = wave_reduce_sum(sq);
    __shared__ float2 ws[4];
    if ((t & 63) == 0) ws[t >> 6] = make_float2(rs, rq);
    __syncthreads();
    if (t == 0) {
        float a = 0.f, q = 0.f;
        for (int k = 0; k < 4; k++) { a += ws[k].x; q += ws[k].y; }
        part[b * 75 + jb] = make_float2(a, q);
    }
}

// ---------------- LN finalize: reduce partials -> (mu, rsqrt(var+eps)) ----------------
__global__ void k_ln_final(const float2* __restrict__ part, int nper, float2* __restrict__ outp) {
    const int b = blockIdx.x, t = threadIdx.x;
    float s = 0.f, sq = 0.f;
    for (int p = t; p < nper; p += 64) {
        float2 v = part[b * nper + p];
        s += v.x; sq += v.y;
    }
    s  = wave_reduce_sum(s);
    sq = wave_reduce_sum(sq);
    if (t == 0) {
        const float invN = 1.f / 1228800.f;
        float mu  = s * invN;
        float var = sq * invN - mu * mu;
        outp[b] = make_float2(mu, rsqrtf(var + EPS_));
    }
}

// ---------------- xw = LN1(x) @ Wih^T + bih ----------------
// grid 2400 (64 rows each), 384 threads; rows flat over (b,sd,sl) = 153600
__global__ __launch_bounds__(384) void k_xw(const float* __restrict__ x,
        const float* __restrict__ g1, const float* __restrict__ b1,
        const float2* __restrict__ s1, const float* __restrict__ Wih,
        const float* __restrict__ bih, float* __restrict__ xw) {
    __shared__ float sWT[64 * 192];  // [c][j]
    __shared__ float sX[64 * 65];    // [r][c] pad 65 (bank spread)
    __shared__ float sB[192];
    const int t = threadIdx.x;
    const int R0 = blockIdx.x * 64;
    for (int idx = t; idx < 12288; idx += 384) {
        int j = idx >> 6, cc = idx & 63;
        sWT[cc * 192 + j] = Wih[idx];
    }
    if (t < 192) sB[t] = bih[t];
    for (int idx = t; idx < 4096; idx += 384) {
        int rr = idx >> 6, cc = idx & 63;
        int row = R0 + rr;
        float2 st = s1[row / 19200];
        int gi = (row % 19200) * 64 + cc;
        sX[rr * 65 + cc] = (x[(size_t)row * 64 + cc] - st.x) * st.y * g1[gi] + b1[gi];
    }
    __syncthreads();
    const int rg = t & 7;
    const int j = (t >> 3) * 4;    // 48 j-groups
    float4 acc[8];
    float4 bj = *(const float4*)&sB[j];
#pragma unroll
    for (int ri = 0; ri < 8; ri++) acc[ri] = bj;
    for (int cc = 0; cc < 64; cc++) {
        float4 w4 = *(const float4*)&sWT[cc * 192 + j];
#pragma unroll
        for (int ri = 0; ri < 8; ri++) {
            float xv = sX[(rg * 8 + ri) * 65 + cc];
            acc[ri].x += xv * w4.x; acc[ri].y += xv * w4.y;
            acc[ri].z += xv * w4.z; acc[ri].w += xv * w4.w;
        }
    }
#pragma unroll
    for (int ri = 0; ri < 8; ri++) {
        int row = R0 + rg * 8 + ri;
        *(float4*)&xw[(size_t)row * 192 + j] = acc[ri];
    }
}

// ---------------- persistent GRU: 200 blocks x 8 sequences, 96 steps in-kernel ----------------
__global__ __launch_bounds__(384) void k_gru(const float* __restrict__ xw,
        const float* __restrict__ x, const float* __restrict__ Whh,
        const float* __restrict__ bhh, float* __restrict__ xr, float2* __restrict__ s2p) {
    __shared__ float sWT[64 * 192];  // WhhT [c][j]
    __shared__ float sH[8 * 68];     // h, pad 68 (16B-aligned rows, bank spread)
    __shared__ float sG[8 * 196];    // gh
    __shared__ float sB[192];
    __shared__ float2 sRed[6];
    const int t = threadIdx.x;
    const int row0 = blockIdx.x * 8;
    for (int idx = t; idx < 12288; idx += 384) {
        int j = idx >> 6, cc = idx & 63;
        sWT[cc * 192 + j] = Whh[idx];
    }
    if (t < 192) sB[t] = bhh[t];
    for (int idx = t; idx < 8 * 68; idx += 384) sH[idx] = 0.f;
    const int r = t & 7;
    const int j = (t >> 3) * 4;
    float lsum = 0.f, lsq = 0.f;
    __syncthreads();
    for (int st = 0; st < 96; st++) {
        // phase 1: gh = h @ Whh^T + bhh
        float4 acc = *(const float4*)&sB[j];
#pragma unroll
        for (int c4 = 0; c4 < 16; c4++) {
            float4 hv = *(const float4*)&sH[r * 68 + c4 * 4];
            const float* wb = &sWT[(c4 * 4) * 192 + j];
            float4 w0 = *(const float4*)&wb[0];
            float4 w1 = *(const float4*)&wb[192];
            float4 w2 = *(const float4*)&wb[384];
            float4 w3 = *(const float4*)&wb[576];
            acc.x += hv.x * w0.x + hv.y * w1.x + hv.z * w2.x + hv.w * w3.x;
            acc.y += hv.x * w0.y + hv.y * w1.y + hv.z * w2.y + hv.w * w3.y;
            acc.z += hv.x * w0.z + hv.y * w1.z + hv.z * w2.z + hv.w * w3.z;
            acc.w += hv.x * w0.w + hv.y * w1.w + hv.z * w2.w + hv.w * w3.w;
        }
        *(float4*)&sG[r * 196 + j] = acc;
        __syncthreads();
        // phase 2: gates + h update + residual out + LN2 partials
        for (int e = t; e < 512; e += 384) {
            int rr = e >> 6, cc = e & 63;
            int rowi = row0 + rr;
            size_t xb = (size_t)rowi * 96 + st;
            const float* xwp = xw + xb * 192;
            float xg = xwp[cc], zg = xwp[64 + cc], ng = xwp[128 + cc];
            float hr_ = sG[rr * 196 + cc];
            float hz  = sG[rr * 196 + 64 + cc];
            float hn  = sG[rr * 196 + 128 + cc];
            float rg_ = 1.f / (1.f + __expf(-(xg + hr_)));
            float zg_ = 1.f / (1.f + __expf(-(zg + hz)));
            float ny = ng + rg_ * hn;
            ny = fminf(fmaxf(ny, -15.f), 15.f);
            float e2 = __expf(-2.f * ny);
            float nv = (1.f - e2) / (1.f + e2);
            float hold = sH[rr * 68 + cc];
            float hnew = nv + zg_ * (hold - nv);
            sH[rr * 68 + cc] = hnew;
            float ov = hnew + x[xb * 64 + cc];
            xr[xb * 64 + cc] = ov;
            lsum += ov; lsq += ov * ov;
        }
        __syncthreads();
    }
    float s = wave_reduce_sum(lsum);
    float q = wave_reduce_sum(lsq);
    if ((t & 63) == 0) sRed[t >> 6] = make_float2(s, q);
    __syncthreads();
    if (t == 0) {
        float a = 0.f, b_ = 0.f;
        for (int k = 0; k < 6; k++) { a += sRed[k].x; b_ += sRed[k].y; }
        s2p[blockIdx.x] = make_float2(a, b_);
    }
}

// ---------------- transpose g2/b2: [64][200][96] -> [96][200][64] ----------------
__global__ void k_tr(const float* __restrict__ in, float* __restrict__ outp) {
    __shared__ float tile[32][33];
    const int v = blockIdx.x;
    const int ct = blockIdx.y & 1;
    const int lt = blockIdx.y >> 1;  // 0..2
    const int t = threadIdx.x;
    const int lx = t & 31, ly = t >> 5;
    const int c0 = ct * 32, l0 = lt * 32;
#pragma unroll
    for (int q = 0; q < 4; q++) {
        int cc = ly + q * 8;
        tile[cc][lx] = in[(size_t)(c0 + cc) * 19200 + (size_t)v * 96 + l0 + lx];
    }
    __syncthreads();
#pragma unroll
    for (int q = 0; q < 4; q++) {
        int ll = ly + q * 8;
        outp[(size_t)(l0 + ll) * 12800 + (size_t)v * 64 + c0 + lx] = tile[lx][ll];
    }
}

// ---------------- static adjacency row-normalize (a and a^T) ----------------
__global__ void k_adj(const float* __restrict__ adj, float* __restrict__ an, float* __restrict__ atn) {
    const int v = blockIdx.x;
    const int mode = blockIdx.y;
    const int t = threadIdx.x;
    float val = 0.f;
    if (t < 200) val = (mode == 0) ? adj[v * 200 + t] : adj[t * 200 + v];
    float s = wave_reduce_sum(val);
    __shared__ float sp[4];
    if ((t & 63) == 0) sp[t >> 6] = s;
    __syncthreads();
    float tot = sp[0] + sp[1] + sp[2] + sp[3] + 1.f;
    if (t < 200) {
        float o = (val + (t == v ? 1.f : 0.f)) / tot;
        if (mode == 0) an[v * 200 + t] = o; else atn[v * 200 + t] = o;
    }
}

// ---------------- dyna graph: inverse (rowsum+1) and (colsum+1) per (b,l) ----------------
__global__ void k_dsum(const float* __restrict__ dyna, float* __restrict__ irs, float* __restrict__ ics) {
    const int blk = blockIdx.x;
    const float* S = dyna + (size_t)blk * 40000;
    const int t = threadIdx.x;
    __shared__ float wp[200 * 4];
    float colacc = 0.f;
    for (int w = 0; w < 200; w++) {
        float v = (t < 200) ? S[w * 200 + t] : 0.f;
        colacc += v;
        float s = wave_reduce_sum(v);
        if ((t & 63) == 0) wp[w * 4 + (t >> 6)] = s;
    }
    __syncthreads();
    if (t < 200) {
        ics[blk * 200 + t] = 1.f / (colacc + 1.f);
        float rs_ = wp[t * 4] + wp[t * 4 + 1] + wp[t * 4 + 2] + wp[t * 4 + 3];
        irs[blk * 200 + t] = 1.f / (rs_ + 1.f);
    }
}

// ---------------- effective projection matrices Mk = Wm_half @ Wg_block ----------------
__global__ void k_meff(const float* __restrict__ Wm, const float* __restrict__ Wg1,
        const float* __restrict__ Wg2, const float* __restrict__ Wd1, const float* __restrict__ Wd2,
        const float* __restrict__ bg1, const float* __restrict__ bg2, const float* __restrict__ bd1,
        const float* __restrict__ bd2, const float* __restrict__ bm,
        float* __restrict__ Meff, float* __restrict__ biasE) {
    const int k = blockIdx.x;
    const int t = threadIdx.x;
    const int o = t >> 2;
    const int cb = (t & 3) * 16;
    float acc[16];
#pragma unroll
    for (int q = 0; q < 16; q++) acc[q] = 0.f;
    if (k == 0) {
        for (int m = 0; m < 64; m++) {
            float aL = Wm[o * 128 + m], aR = Wm[o * 128 + 64 + m];
#pragma unroll
            for (int q = 0; q < 16; q++) {
                int cc = cb + q;
                acc[q] += aL * (Wg1[m * 192 + cc] + Wg2[m * 192 + cc])
                        + aR * (Wd1[m * 192 + cc] + Wd2[m * 192 + cc]);
            }
        }
    } else {
        const float* Ws = (k <= 2) ? Wg1 : (k <= 4) ? Wg2 : (k <= 6) ? Wd1 : Wd2;
        const int side = (k <= 4) ? 0 : 64;
        const int hop = (((k - 1) & 1) == 0) ? 64 : 128;
        for (int m = 0; m < 64; m++) {
            float a_ = Wm[o * 128 + side + m];
#pragma unroll
            for (int q = 0; q < 16; q++) acc[q] += a_ * Ws[m * 192 + hop + cb + q];
        }
    }
#pragma unroll
    for (int q = 0; q < 16; q++) Meff[k * 4096 + o * 64 + cb + q] = acc[q];
    if (k == 0 && t < 64) {
        float s = bm[t];
        for (int cc = 0; cc < 64; cc++)
            s += Wm[t * 128 + cc] * (bg1[cc] + bg2[cc]) + Wm[t * 128 + 64 + cc] * (bd1[cc] + bd2[cc]);
        biasE[t] = s;
    }
}

// ---------------- nx[b,l,v,c] = LN2(xr) with transposed gamma/beta ----------------
__global__ void k_nx(const float4* __restrict__ xr4, const float2* __restrict__ s2,
        const float4* __restrict__ g2t4, const float4* __restrict__ b2t4, float4* __restrict__ nx4) {
    size_t id = (size_t)blockIdx.x * 256 + threadIdx.x;  // < 2457600
    int cf = (int)(id & 15);
    size_t grp = id >> 4;
    int v = (int)(grp % 200);
    size_t bl = grp / 200;
    int l = (int)(bl % 96);
    int b = (int)(bl / 96);
    float2 st = s2[b];
    float4 xv = xr4[(((size_t)(b * 200 + v)) * 96 + l) * 16 + cf];
    size_t gi = ((size_t)l * 200 + v) * 16 + cf;
    float4 g = g2t4[gi];
    float4 bb = b2t4[gi];
    float4 o;
    o.x = (xv.x - st.x) * st.y * g.x + bb.x;
    o.y = (xv.y - st.x) * st.y * g.y + bb.y;
    o.z = (xv.z - st.x) * st.y * g.z + bb.z;
    o.w = (xv.w - st.x) * st.y * g.w + bb.w;
    nx4[id] = o;
}

// ---------------- per-(b,l) graph kernel: 8 hops + 9 projections + merge + residual ----------------
// MODE 0: static row-major A (diag folded in). MODE 1: dyna rows (+diag, *irs). MODE 2: dyna cols (+diag, *ics).
template <int MODE>
__device__ __forceinline__ void prop_hop(float* __restrict__ Hdst, const float* __restrict__ Hsrc,
        const float* __restrict__ A, const float* __restrict__ invs,
        const float* __restrict__ h0own, int v0, int c) {
    float acc[25];
#pragma unroll
    for (int i = 0; i < 25; i++) acc[i] = 0.f;
    if (MODE == 2) {
        for (int w = 0; w < 200; w++) {
            float hcw = Hsrc[w * 64 + c];
            const float* Ar = A + (size_t)w * 200 + v0;
#pragma unroll
            for (int i = 0; i < 25; i++) acc[i] += Ar[i] * hcw;
        }
    } else {
        for (int w = 0; w < 200; w += 4) {
            float hc0 = Hsrc[(w + 0) * 64 + c];
            float hc1 = Hsrc[(w + 1) * 64 + c];
            float hc2 = Hsrc[(w + 2) * 64 + c];
            float hc3 = Hsrc[(w + 3) * 64 + c];
#pragma unroll
            for (int i = 0; i < 25; i++) {
                float4 a4 = *(const float4*)(A + (size_t)(v0 + i) * 200 + w);
                acc[i] += a4.x * hc0 + a4.y * hc1 + a4.z * hc2 + a4.w * hc3;
            }
        }
    }
#pragma unroll
    for (int i = 0; i < 25; i++) {
        const int v = v0 + i;
        float s = acc[i];
        if (MODE >= 1) s = (s + Hsrc[v * 64 + c]) * invs[v];
        Hdst[v * 64 + c] = ALPHA_ * h0own[i] + BETA_ * s;
    }
}

__device__ __forceinline__ void proj_acc(const float* __restrict__ Hsrc,
        const float* __restrict__ Mk, int v0, int c, float* __restrict__ ACC) {
    const float4* Mr = (const float4*)(Mk + c * 64);
    for (int q = 0; q < 16; q++) {
        float4 m4 = Mr[q];
#pragma unroll
        for (int i = 0; i < 25; i++) {
            float4 h4 = *(const float4*)(Hsrc + (v0 + i) * 64 + q * 4);
            ACC[i] += h4.x * m4.x + h4.y * m4.y + h4.z * m4.z + h4.w * m4.w;
        }
    }
}

__global__ __launch_bounds__(512) void k_graph(const float* __restrict__ nx,
        const float* __restrict__ xrb, const float* __restrict__ an, const float* __restrict__ atn,
        const float* __restrict__ dyna, const float* __restrict__ irs, const float* __restrict__ ics,
        const float* __restrict__ Meff, const float* __restrict__ biasE, float* __restrict__ out) {
    __shared__ float sh[38400];  // 150 KiB: H0 | HA | HB, each [200][64]
    float* H0 = sh;
    float* HA = sh + 12800;
    float* HB = sh + 25600;
    const int blk = blockIdx.x;
    const int b = blk / 96, l = blk % 96;
    const int t = threadIdx.x;
    const int c = t & 63;
    const int v0 = (t >> 6) * 25;
    const float* nxs = nx + (size_t)blk * 12800;
    for (int i = t; i < 12800; i += 512) H0[i] = nxs[i];
    __syncthreads();
    float h0own[25], ACC[25];
#pragma unroll
    for (int i = 0; i < 25; i++) { h0own[i] = H0[(v0 + i) * 64 + c]; ACC[i] = 0.f; }
    proj_acc(H0, Meff, v0, c, ACC);
    // chain a
    prop_hop<0>(HA, H0, an, nullptr, h0own, v0, c);
    __syncthreads();
    proj_acc(HA, Meff + 1 * 4096, v0, c, ACC);
    prop_hop<0>(HB, HA, an, nullptr, h0own, v0, c);
    __syncthreads();
    proj_acc(HB, Meff + 2 * 4096, v0, c, ACC);
    // chain a^T
    prop_hop<0>(HA, H0, atn, nullptr, h0own, v0, c);
    __syncthreads();
    proj_acc(HA, Meff + 3 * 4096, v0, c, ACC);
    prop_hop<0>(HB, HA, atn, nullptr, h0own, v0, c);
    __syncthreads();
    proj_acc(HB, Meff + 4 * 4096, v0, c, ACC);
    // dyna chains
    const float* S = dyna + (size_t)blk * 40000;
    const float* irsb = irs + blk * 200;
    const float* icsb = ics + blk * 200;
    prop_hop<1>(HA, H0, S, irsb, h0own, v0, c);
    __syncthreads();
    proj_acc(HA, Meff + 5 * 4096, v0, c, ACC);
    prop_hop<1>(HB, HA, S, irsb, h0own, v0, c);
    __syncthreads();
    proj_acc(HB, Meff + 6 * 4096, v0, c, ACC);
    prop_hop<2>(HA, H0, S, icsb, h0own, v0, c);
    __syncthreads();
    proj_acc(HA, Meff + 7 * 4096, v0, c, ACC);
    prop_hop<2>(HB, HA, S, icsb, h0own, v0, c);
    __syncthreads();
    proj_acc(HB, Meff + 8 * 4096, v0, c, ACC);
    // merge + bias + residual
    float bE = biasE[c];
#pragma unroll
    for (int i = 0; i < 25; i++) {
        int v = v0 + i;
        size_t oi = (((size_t)(b * 200 + v)) * 96 + l) * 64 + c;
        out[oi] = ACC[i] + bE + xrb[oi];
    }
}

extern "C" void kernel_launch(void* const* d_in, const int* in_sizes, int n_in,
                              void* d_out, int out_size, void* d_ws, size_t ws_size,
                              hipStream_t stream) {
    (void)in_sizes; (void)n_in; (void)out_size; (void)ws_size;
    const float* x    = (const float*)d_in[0];
    const float* adj  = (const float*)d_in[1];
    const float* dyna = (const float*)d_in[2];
    const float* g1   = (const float*)d_in[3];
    const float* b1   = (const float*)d_in[4];
    const float* g2   = (const float*)d_in[5];
    const float* b2   = (const float*)d_in[6];
    const float* Wih  = (const float*)d_in[7];
    const float* Whh  = (const float*)d_in[8];
    const float* bih  = (const float*)d_in[9];
    const float* bhh  = (const float*)d_in[10];
    const float* Wg1  = (const float*)d_in[11];
    const float* bg1  = (const float*)d_in[12];
    const float* Wg2  = (const float*)d_in[13];
    const float* bg2  = (const float*)d_in[14];
    const float* Wd1  = (const float*)d_in[15];
    const float* bd1  = (const float*)d_in[16];
    const float* Wd2  = (const float*)d_in[17];
    const float* bd2  = (const float*)d_in[18];
    const float* Wm   = (const float*)d_in[19];
    const float* bm   = (const float*)d_in[20];
    float* out = (float*)d_out;
    float* ws = (float*)d_ws;

    float* xw    = ws;                    // 29,491,200
    float* xr    = ws + 29491200;         //  9,830,400
    float* nx    = ws + 39321600;         //  9,830,400
    float* g2t   = ws + 49152000;         //  1,228,800
    float* b2t   = ws + 50380800;         //  1,228,800
    float* an    = ws + 51609600;         //     40,000
    float* atn   = ws + 51649600;         //     40,000
    float* irs   = ws + 51689600;         //    153,600
    float* ics   = ws + 51843200;         //    153,600
    float* Meff  = ws + 51996800;         //     36,864
    float* biasE = ws + 52033664;         //         64
    float2* s1p  = (float2*)(ws + 52033728); // 600 float2
    float2* s1   = (float2*)(ws + 52034928); //   8 float2
    float2* s2p  = (float2*)(ws + 52034944); // 200 float2
    float2* s2   = (float2*)(ws + 52035344); //   8 float2
    // total ~208.1 MB of workspace

    k_ln_part<<<dim3(75, 8), dim3(256), 0, stream>>>((const float4*)x, s1p);
    k_ln_final<<<dim3(8), dim3(64), 0, stream>>>(s1p, 75, s1);
    k_xw<<<dim3(2400), dim3(384), 0, stream>>>(x, g1, b1, s1, Wih, bih, xw);
    k_gru<<<dim3(200), dim3(384), 0, stream>>>(xw, x, Whh, bhh, xr, s2p);
    k_ln_final<<<dim3(8), dim3(64), 0, stream>>>(s2p, 25, s2);
    k_tr<<<dim3(200, 6), dim3(256), 0, stream>>>(g2, g2t);
    k_tr<<<dim3(200, 6), dim3(256), 0, stream>>>(b2, b2t);
    k_adj<<<dim3(200, 2), dim3(256), 0, stream>>>(adj, an, atn);
    k_dsum<<<dim3(768), dim3(256), 0, stream>>>(dyna, irs, ics);
    k_meff<<<dim3(9), dim3(256), 0, stream>>>(Wm, Wg1, Wg2, Wd1, Wd2, bg1, bg2, bd1, bd2, bm, Meff, biasE);
    k_nx<<<dim3(9600), dim3(256), 0, stream>>>((const float4*)xr, s2, (const float4*)g2t, (const float4*)b2t, (float4*)nx);
    k_graph<<<dim3(768), dim3(512), 0, stream>>>(nx, xr, an, atn, dyna, irs, ics, Meff, biasE, out);
}

// Round 3
// 802.940 us; speedup vs baseline: 4.1782x; 4.1782x over previous
//
#include <hip/hip_runtime.h>
#include <math.h>

#define ALPHA_ 0.1f
#define BETA_  0.9f
#define EPS_   1e-5f

typedef __bf16 bf16x8 __attribute__((ext_vector_type(8)));
typedef float f32x16 __attribute__((ext_vector_type(16)));

__device__ __forceinline__ unsigned short f2bf(float f) {
    return __builtin_bit_cast(unsigned short, (__bf16)f);
}
__device__ __forceinline__ float bf2f(unsigned short u) {
    return (float)__builtin_bit_cast(__bf16, u);
}

__device__ __forceinline__ float wave_reduce_sum(float v) {
#pragma unroll
    for (int off = 32; off > 0; off >>= 1) v += __shfl_down(v, off, 64);
    return v;
}

// ---------------- LN partial sums (per-b mean/var, stage 1) ----------------
__global__ void k_ln_part(const float4* __restrict__ x4, float2* __restrict__ part) {
    const int b = blockIdx.y, jb = blockIdx.x, t = threadIdx.x;
    const size_t base = (size_t)b * 307200 + (size_t)jb * 4096;
    float s = 0.f, sq = 0.f;
#pragma unroll
    for (int k = 0; k < 16; k++) {
        float4 v = x4[base + k * 256 + t];
        s  += v.x + v.y + v.z + v.w;
        sq += v.x * v.x + v.y * v.y + v.z * v.z + v.w * v.w;
    }
    float rs = wave_reduce_sum(s);
    float rq = wave_reduce_sum(sq);
    __shared__ float2 ws[4];
    if ((t & 63) == 0) ws[t >> 6] = make_float2(rs, rq);
    __syncthreads();
    if (t == 0) {
        float a = 0.f, q = 0.f;
        for (int k = 0; k < 4; k++) { a += ws[k].x; q += ws[k].y; }
        part[b * 75 + jb] = make_float2(a, q);
    }
}

__global__ void k_ln_final(const float2* __restrict__ part, int nper, float2* __restrict__ outp) {
    const int b = blockIdx.x, t = threadIdx.x;
    float s = 0.f, sq = 0.f;
    for (int p = t; p < nper; p += 64) {
        float2 v = part[b * nper + p];
        s += v.x; sq += v.y;
    }
    s  = wave_reduce_sum(s);
    sq = wave_reduce_sum(sq);
    if (t == 0) {
        const float invN = 1.f / 1228800.f;
        float mu  = s * invN;
        float var = sq * invN - mu * mu;
        outp[b] = make_float2(mu, rsqrtf(var + EPS_));
    }
}

// ---------------- xw = LN1(x) @ Wih^T + bih ----------------
__global__ __launch_bounds__(384) void k_xw(const float* __restrict__ x,
        const float* __restrict__ g1, const float* __restrict__ b1,
        const float2* __restrict__ s1, const float* __restrict__ Wih,
        const float* __restrict__ bih, float* __restrict__ xw) {
    __shared__ float sWT[64 * 192];
    __shared__ float sX[64 * 65];
    __shared__ float sB[192];
    const int t = threadIdx.x;
    const int R0 = blockIdx.x * 64;
    for (int idx = t; idx < 12288; idx += 384) {
        int j = idx >> 6, cc = idx & 63;
        sWT[cc * 192 + j] = Wih[idx];
    }
    if (t < 192) sB[t] = bih[t];
    for (int idx = t; idx < 4096; idx += 384) {
        int rr = idx >> 6, cc = idx & 63;
        int row = R0 + rr;
        float2 st = s1[row / 19200];
        int gi = (row % 19200) * 64 + cc;
        sX[rr * 65 + cc] = (x[(size_t)row * 64 + cc] - st.x) * st.y * g1[gi] + b1[gi];
    }
    __syncthreads();
    const int rg = t & 7;
    const int j = (t >> 3) * 4;
    float4 acc[8];
    float4 bj = *(const float4*)&sB[j];
#pragma unroll
    for (int ri = 0; ri < 8; ri++) acc[ri] = bj;
    for (int cc = 0; cc < 64; cc++) {
        float4 w4 = *(const float4*)&sWT[cc * 192 + j];
#pragma unroll
        for (int ri = 0; ri < 8; ri++) {
            float xv = sX[(rg * 8 + ri) * 65 + cc];
            acc[ri].x += xv * w4.x; acc[ri].y += xv * w4.y;
            acc[ri].z += xv * w4.z; acc[ri].w += xv * w4.w;
        }
    }
#pragma unroll
    for (int ri = 0; ri < 8; ri++) {
        int row = R0 + rg * 8 + ri;
        *(float4*)&xw[(size_t)row * 192 + j] = acc[ri];
    }
}

// ---------------- persistent GRU ----------------
__global__ __launch_bounds__(384) void k_gru(const float* __restrict__ xw,
        const float* __restrict__ x, const float* __restrict__ Whh,
        const float* __restrict__ bhh, float* __restrict__ xr, float2* __restrict__ s2p) {
    __shared__ float sWT[64 * 192];
    __shared__ float sH[8 * 68];
    __shared__ float sG[8 * 196];
    __shared__ float sB[192];
    __shared__ float2 sRed[6];
    const int t = threadIdx.x;
    const int row0 = blockIdx.x * 8;
    for (int idx = t; idx < 12288; idx += 384) {
        int j = idx >> 6, cc = idx & 63;
        sWT[cc * 192 + j] = Whh[idx];
    }
    if (t < 192) sB[t] = bhh[t];
    for (int idx = t; idx < 8 * 68; idx += 384) sH[idx] = 0.f;
    const int r = t & 7;
    const int j = (t >> 3) * 4;
    float lsum = 0.f, lsq = 0.f;
    __syncthreads();
    for (int st = 0; st < 96; st++) {
        float4 acc = *(const float4*)&sB[j];
#pragma unroll
        for (int c4 = 0; c4 < 16; c4++) {
            float4 hv = *(const float4*)&sH[r * 68 + c4 * 4];
            const float* wb = &sWT[(c4 * 4) * 192 + j];
            float4 w0 = *(const float4*)&wb[0];
            float4 w1 = *(const float4*)&wb[192];
            float4 w2 = *(const float4*)&wb[384];
            float4 w3 = *(const float4*)&wb[576];
            acc.x += hv.x * w0.x + hv.y * w1.x + hv.z * w2.x + hv.w * w3.x;
            acc.y += hv.x * w0.y + hv.y * w1.y + hv.z * w2.y + hv.w * w3.y;
            acc.z += hv.x * w0.z + hv.y * w1.z + hv.z * w2.z + hv.w * w3.z;
            acc.w += hv.x * w0.w + hv.y * w1.w + hv.z * w2.w + hv.w * w3.w;
        }
        *(float4*)&sG[r * 196 + j] = acc;
        __syncthreads();
        for (int e = t; e < 512; e += 384) {
            int rr = e >> 6, cc = e & 63;
            int rowi = row0 + rr;
            size_t xb = (size_t)rowi * 96 + st;
            const float* xwp = xw + xb * 192;
            float xg = xwp[cc], zg = xwp[64 + cc], ng = xwp[128 + cc];
            float hr_ = sG[rr * 196 + cc];
            float hz  = sG[rr * 196 + 64 + cc];
            float hn  = sG[rr * 196 + 128 + cc];
            float rg_ = 1.f / (1.f + __expf(-(xg + hr_)));
            float zg_ = 1.f / (1.f + __expf(-(zg + hz)));
            float ny = ng + rg_ * hn;
            ny = fminf(fmaxf(ny, -15.f), 15.f);
            float e2 = __expf(-2.f * ny);
            float nv = (1.f - e2) / (1.f + e2);
            float hold = sH[rr * 68 + cc];
            float hnew = nv + zg_ * (hold - nv);
            sH[rr * 68 + cc] = hnew;
            float ov = hnew + x[xb * 64 + cc];
            xr[xb * 64 + cc] = ov;
            lsum += ov; lsq += ov * ov;
        }
        __syncthreads();
    }
    float s = wave_reduce_sum(lsum);
    float q = wave_reduce_sum(lsq);
    if ((t & 63) == 0) sRed[t >> 6] = make_float2(s, q);
    __syncthreads();
    if (t == 0) {
        float a = 0.f, b_ = 0.f;
        for (int k = 0; k < 6; k++) { a += sRed[k].x; b_ += sRed[k].y; }
        s2p[blockIdx.x] = make_float2(a, b_);
    }
}

// ---------------- transpose g2/b2: [64][200][96] -> [96][200][64] ----------------
__global__ void k_tr(const float* __restrict__ in, float* __restrict__ outp) {
    __shared__ float tile[32][33];
    const int v = blockIdx.x;
    const int ct = blockIdx.y & 1;
    const int lt = blockIdx.y >> 1;
    const int t = threadIdx.x;
    const int lx = t & 31, ly = t >> 5;
    const int c0 = ct * 32, l0 = lt * 32;
#pragma unroll
    for (int q = 0; q < 4; q++) {
        int cc = ly + q * 8;
        tile[cc][lx] = in[(size_t)(c0 + cc) * 19200 + (size_t)v * 96 + l0 + lx];
    }
    __syncthreads();
#pragma unroll
    for (int q = 0; q < 4; q++) {
        int ll = ly + q * 8;
        outp[(size_t)(l0 + ll) * 12800 + (size_t)v * 64 + c0 + lx] = tile[lx][ll];
    }
}

// ---------------- static adjacency -> normalized bf16, padded [224][208] ----------------
__global__ void k_adjprep(const float* __restrict__ adj, unsigned short* __restrict__ an_b,
        unsigned short* __restrict__ atn_b) {
    const int v = blockIdx.x;      // 0..223
    const int mode = blockIdx.y;
    const int t = threadIdx.x;     // 256
    unsigned short* outp = (mode == 0) ? an_b : atn_b;
    if (v >= 200) { if (t < 208) outp[v * 208 + t] = 0; return; }
    float val = 0.f;
    if (t < 200) val = (mode == 0) ? adj[v * 200 + t] : adj[t * 200 + v];
    float s = wave_reduce_sum(val);
    __shared__ float sp[4];
    if ((t & 63) == 0) sp[t >> 6] = s;
    __syncthreads();
    float inv = 1.f / (sp[0] + sp[1] + sp[2] + sp[3] + 1.f);
    if (t < 208) {
        float o = (t < 200) ? (val + (t == v ? 1.f : 0.f)) * inv : 0.f;
        outp[v * 208 + t] = f2bf(o);
    }
}

// ---------------- dyna graph -> normalized bf16 danr/danc, per-(b,l) [200][208] ----------------
__global__ __launch_bounds__(256) void k_dprep(const float* __restrict__ dyna,
        unsigned short* __restrict__ danr, unsigned short* __restrict__ danc) {
    __shared__ float sS[40000];
    __shared__ float sinv[400];
    const int blk = blockIdx.x;
    const int t = threadIdx.x;
    const float* S = dyna + (size_t)blk * 40000;
    for (int idx = t; idx < 40000; idx += 256) sS[idx] = S[idx];
    __syncthreads();
    if (t < 200) {
        float rs = 0.f, cs = 0.f;
        for (int w = 0; w < 200; w++) { rs += sS[t * 200 + w]; cs += sS[w * 200 + t]; }
        sinv[t] = 1.f / (rs + 1.f);
        sinv[200 + t] = 1.f / (cs + 1.f);
    }
    __syncthreads();
    unsigned short* dr = danr + (size_t)blk * 41600;
    unsigned short* dc = danc + (size_t)blk * 41600;
    for (int v = 0; v < 200; v++) {
        if (t < 208) {
            float vr = 0.f, vc = 0.f;
            if (t < 200) {
                float d = (t == v) ? 1.f : 0.f;
                vr = (sS[v * 200 + t] + d) * sinv[v];
                vc = (sS[t * 200 + v] + d) * sinv[200 + v];
            }
            dr[v * 208 + t] = f2bf(vr);
            dc[v * 208 + t] = f2bf(vc);
        }
    }
    if (blk == 767) {  // zero the 24-row tail read by padded A-row fetches of the last block
        for (int idx = t; idx < 4992; idx += 256) {
            danr[(size_t)768 * 41600 + idx] = 0;
            danc[(size_t)768 * 41600 + idx] = 0;
        }
    }
}

// ---------------- effective projection matrices -> bf16 MeffB[9][64][64] + biasE ----------------
__global__ void k_meff(const float* __restrict__ Wm, const float* __restrict__ Wg1,
        const float* __restrict__ Wg2, const float* __restrict__ Wd1, const float* __restrict__ Wd2,
        const float* __restrict__ bg1, const float* __restrict__ bg2, const float* __restrict__ bd1,
        const float* __restrict__ bd2, const float* __restrict__ bm,
        unsigned short* __restrict__ MeffB, float* __restrict__ biasE) {
    const int k = blockIdx.x;
    const int t = threadIdx.x;
    const int o = t >> 2;
    const int cb = (t & 3) * 16;
    float acc[16];
#pragma unroll
    for (int q = 0; q < 16; q++) acc[q] = 0.f;
    if (k == 0) {
        for (int m = 0; m < 64; m++) {
            float aL = Wm[o * 128 + m], aR = Wm[o * 128 + 64 + m];
#pragma unroll
            for (int q = 0; q < 16; q++) {
                int cc = cb + q;
                acc[q] += aL * (Wg1[m * 192 + cc] + Wg2[m * 192 + cc])
                        + aR * (Wd1[m * 192 + cc] + Wd2[m * 192 + cc]);
            }
        }
    } else {
        const float* Ws = (k <= 2) ? Wg1 : (k <= 4) ? Wg2 : (k <= 6) ? Wd1 : Wd2;
        const int side = (k <= 4) ? 0 : 64;
        const int hop = (((k - 1) & 1) == 0) ? 64 : 128;
        for (int m = 0; m < 64; m++) {
            float a_ = Wm[o * 128 + side + m];
#pragma unroll
            for (int q = 0; q < 16; q++) acc[q] += a_ * Ws[m * 192 + hop + cb + q];
        }
    }
#pragma unroll
    for (int q = 0; q < 16; q++) MeffB[k * 4096 + o * 64 + cb + q] = f2bf(acc[q]);
    if (k == 0 && t < 64) {
        float s = bm[t];
        for (int cc = 0; cc < 64; cc++)
            s += Wm[t * 128 + cc] * (bg1[cc] + bg2[cc]) + Wm[t * 128 + 64 + cc] * (bd1[cc] + bd2[cc]);
        biasE[t] = s;
    }
}

// ---------------- nx (bf16) = LN2(xr), layout [b*96+l][v][c] ----------------
__global__ void k_nx(const float4* __restrict__ xr4, const float2* __restrict__ s2,
        const float4* __restrict__ g2t4, const float4* __restrict__ b2t4,
        unsigned short* __restrict__ nxb) {
    size_t id = (size_t)blockIdx.x * 256 + threadIdx.x;  // < 2457600
    int cf = (int)(id & 15);
    size_t grp = id >> 4;
    int v = (int)(grp % 200);
    size_t bl = grp / 200;
    int l = (int)(bl % 96);
    int b = (int)(bl / 96);
    float2 st = s2[b];
    float4 xv = xr4[(((size_t)(b * 200 + v)) * 96 + l) * 16 + cf];
    size_t gi = ((size_t)l * 200 + v) * 16 + cf;
    float4 g = g2t4[gi];
    float4 bb = b2t4[gi];
    unsigned int lo = (unsigned)f2bf((xv.x - st.x) * st.y * g.x + bb.x)
                    | ((unsigned)f2bf((xv.y - st.x) * st.y * g.y + bb.y) << 16);
    unsigned int hi = (unsigned)f2bf((xv.z - st.x) * st.y * g.z + bb.z)
                    | ((unsigned)f2bf((xv.w - st.x) * st.y * g.w + bb.w) << 16);
    ((uint2*)nxb)[id] = make_uint2(lo, hi);
}

// ================= MFMA graph kernel =================
#define OFF_HT0 0
#define OFF_H0R 32768
#define OFF_HT1 61440
#define OFF_H1R 94208
#define OFF_H2R 122880
#define OFF_OBUF 61440
#define SMEM_SZ 151552

__device__ __forceinline__ int ht_addr(int c, int w) {
    return (c * 512 + w * 2) ^ (((c >> 2) & 7) << 4);
}
__device__ __forceinline__ int hr_addr(int v, int c) {
    return (v * 128 + c * 2) ^ ((v & 7) << 4);
}

__device__ __forceinline__ void prop_store(unsigned char* smem, const f32x16& acc, int mt, int ct,
        int ln, int half, int dstHt, int dstHr) {
    const int c = ct * 32 + ln;
#pragma unroll
    for (int g = 0; g < 4; g++) {
        const int vb = mt * 32 + half * 4 + g * 8;
        if (vb < 200) {
            unsigned short pk[4];
#pragma unroll
            for (int i = 0; i < 4; i++) {
                const int v = vb + i;
                float h0 = bf2f(*(const unsigned short*)(smem + OFF_H0R + hr_addr(v, c)));
                float hn = ALPHA_ * h0 + BETA_ * acc[g * 4 + i];
                unsigned short bv = f2bf(hn);
                pk[i] = bv;
                *(unsigned short*)(smem + dstHr + hr_addr(v, c)) = bv;
            }
            if (dstHt >= 0) {
                *(uint2*)(smem + dstHt + ht_addr(c, vb)) = make_uint2(
                    (unsigned)pk[0] | ((unsigned)pk[1] << 16),
                    (unsigned)pk[2] | ((unsigned)pk[3] << 16));
            }
        }
    }
}

__device__ __forceinline__ void prop_full(unsigned char* smem, const unsigned short* __restrict__ A,
        int srcHt, int dstHt, int dstHr, int wid, int ln, int half) {
    const int ct = wid & 1;
    const int mt0 = wid >> 1;
    const bool has2 = (wid < 6);
    const int c = ct * 32 + ln;
    f32x16 acc0 = {}; f32x16 acc1 = {};
    const unsigned short* A0p = A + (size_t)(mt0 * 32 + ln) * 208;
    const unsigned short* A1p = A + (size_t)((mt0 + 4) * 32 + ln) * 208;
#pragma unroll
    for (int kk = 0; kk < 13; kk++) {
        const int k0 = kk * 16 + half * 8;
        bf16x8 bf = __builtin_bit_cast(bf16x8, *(const uint4*)(smem + srcHt + ht_addr(c, k0)));
        bf16x8 a0 = __builtin_bit_cast(bf16x8, *(const uint4*)(const void*)(A0p + k0));
        acc0 = __builtin_amdgcn_mfma_f32_32x32x16_bf16(a0, bf, acc0, 0, 0, 0);
        if (has2) {
            bf16x8 a1 = __builtin_bit_cast(bf16x8, *(const uint4*)(const void*)(A1p + k0));
            acc1 = __builtin_amdgcn_mfma_f32_32x32x16_bf16(a1, bf, acc1, 0, 0, 0);
        }
    }
    prop_store(smem, acc0, mt0, ct, ln, half, dstHt, dstHr);
    if (has2) prop_store(smem, acc1, mt0 + 4, ct, ln, half, dstHt, dstHr);
}

__device__ __forceinline__ void proj_step(unsigned char* smem, const unsigned short* __restrict__ MB,
        int srcHr, int wid, int ln, int half, f32x16& A0, f32x16& A1) {
    const int mtO = wid & 1;
    const int nt0 = wid >> 1;
    const bool has2 = (wid < 6);
    const int o = mtO * 32 + ln;
    const int va = nt0 * 32 + ln;
    const int vb = (nt0 + 4) * 32 + ln;
#pragma unroll
    for (int kk = 0; kk < 4; kk++) {
        const int c0 = kk * 16 + half * 8;
        bf16x8 mf = __builtin_bit_cast(bf16x8, *(const uint4*)(const void*)(MB + o * 64 + c0));
        bf16x8 h0 = __builtin_bit_cast(bf16x8, *(const uint4*)(smem + srcHr + hr_addr(va, c0)));
        A0 = __builtin_amdgcn_mfma_f32_32x32x16_bf16(mf, h0, A0, 0, 0, 0);
        if (has2) {
            bf16x8 h1 = __builtin_bit_cast(bf16x8, *(const uint4*)(smem + srcHr + hr_addr(vb, c0)));
            A1 = __builtin_amdgcn_mfma_f32_32x32x16_bf16(mf, h1, A1, 0, 0, 0);
        }
    }
}

__device__ __forceinline__ void store_obuf(unsigned char* smem, const f32x16& acc, int mtO, int ntV,
        int ln, int half) {
    const int v = ntV * 32 + ln;
    if (v >= 200) return;
#pragma unroll
    for (int r = 0; r < 16; r++) {
        const int o = mtO * 32 + half * 4 + (r & 3) + (r >> 2) * 8;
        *(float*)(smem + OFF_OBUF + (o * 200 + v) * 4) = acc[r];
    }
}

__global__ __launch_bounds__(512, 2) void k_graph2(const unsigned short* __restrict__ nxb,
        const float* __restrict__ xrb, const unsigned short* __restrict__ an_b,
        const unsigned short* __restrict__ atn_b, const unsigned short* __restrict__ danr_b,
        const unsigned short* __restrict__ danc_b, const unsigned short* __restrict__ MeffB,
        const float* __restrict__ biasE, float* __restrict__ out) {
    __shared__ __align__(16) unsigned char smem[SMEM_SZ];
    const int blk = blockIdx.x;
    const int b = blk / 96, l = blk % 96;
    const int t = threadIdx.x;
    const int wid = t >> 6, lane = t & 63, ln = lane & 31, half = lane >> 5;

    const unsigned int* nxs = (const unsigned int*)(nxb + (size_t)blk * 12800);
    for (int idx = t; idx < 6400; idx += 512) {
        unsigned int val = nxs[idx];
        int v = idx >> 5, c2 = (idx & 31) * 2;
        *(unsigned int*)(smem + OFF_H0R + hr_addr(v, c2)) = val;
        *(unsigned short*)(smem + OFF_HT0 + ht_addr(c2, v)) = (unsigned short)(val & 0xffffu);
        *(unsigned short*)(smem + OFF_HT0 + ht_addr(c2 + 1, v)) = (unsigned short)(val >> 16);
    }
    for (int idx = t; idx < 768; idx += 512) {
        int v = 200 + (idx >> 5), c2 = (idx & 31) * 2;
        *(unsigned int*)(smem + OFF_H0R + hr_addr(v, c2)) = 0;
    }
    if (t < 512) {
        int c = t >> 3, w = 200 + (t & 7);
        *(unsigned short*)(smem + OFF_HT0 + ht_addr(c, w)) = 0;
        *(unsigned short*)(smem + OFF_HT1 + ht_addr(c, w)) = 0;
    }
    __syncthreads();

    f32x16 ACC0 = {}; f32x16 ACC1 = {};
    proj_step(smem, MeffB, OFF_H0R, wid, ln, half, ACC0, ACC1);

#pragma unroll 1
    for (int chain = 0; chain < 4; chain++) {
        const unsigned short* A = (chain == 0) ? an_b : (chain == 1) ? atn_b
            : (chain == 2) ? (danr_b + (size_t)blk * 41600) : (danc_b + (size_t)blk * 41600);
        prop_full(smem, A, OFF_HT0, OFF_HT1, OFF_H1R, wid, ln, half);
        __syncthreads();
        proj_step(smem, MeffB + (size_t)(1 + 2 * chain) * 4096, OFF_H1R, wid, ln, half, ACC0, ACC1);
        prop_full(smem, A, OFF_HT1, -1, OFF_H2R, wid, ln, half);
        __syncthreads();
        proj_step(smem, MeffB + (size_t)(2 + 2 * chain) * 4096, OFF_H2R, wid, ln, half, ACC0, ACC1);
    }

    {
        const int mtO = wid & 1, nt0 = wid >> 1;
        store_obuf(smem, ACC0, mtO, nt0, ln, half);
        if (wid < 6) store_obuf(smem, ACC1, mtO, nt0 + 4, ln, half);
    }
    __syncthreads();

    const size_t gbase = ((size_t)b * 200 * 96 + l) * 64;
    for (int idx = t; idx < 12800; idx += 512) {
        int v = idx >> 6, o = idx & 63;
        float val = *(const float*)(smem + OFF_OBUF + (o * 200 + v) * 4) + biasE[o];
        size_t gi = gbase + (size_t)v * 6144 + o;
        out[gi] = val + xrb[gi];
    }
}

extern "C" void kernel_launch(void* const* d_in, const int* in_sizes, int n_in,
                              void* d_out, int out_size, void* d_ws, size_t ws_size,
                              hipStream_t stream) {
    (void)in_sizes; (void)n_in; (void)out_size; (void)ws_size;
    const float* x    = (const float*)d_in[0];
    const float* adj  = (const float*)d_in[1];
    const float* dyna = (const float*)d_in[2];
    const float* g1   = (const float*)d_in[3];
    const float* b1   = (const float*)d_in[4];
    const float* g2   = (const float*)d_in[5];
    const float* b2   = (const float*)d_in[6];
    const float* Wih  = (const float*)d_in[7];
    const float* Whh  = (const float*)d_in[8];
    const float* bih  = (const float*)d_in[9];
    const float* bhh  = (const float*)d_in[10];
    const float* Wg1  = (const float*)d_in[11];
    const float* bg1  = (const float*)d_in[12];
    const float* Wg2  = (const float*)d_in[13];
    const float* bg2  = (const float*)d_in[14];
    const float* Wd1  = (const float*)d_in[15];
    const float* bd1  = (const float*)d_in[16];
    const float* Wd2  = (const float*)d_in[17];
    const float* bd2  = (const float*)d_in[18];
    const float* Wm   = (const float*)d_in[19];
    const float* bm   = (const float*)d_in[20];
    float* out = (float*)d_out;
    float* ws = (float*)d_ws;

    float*          xr    = ws;                                   // 9,830,400
    unsigned short* nxb   = (unsigned short*)(ws + 9830400);      // 9,830,400 bf16
    float*          g2t   = ws + 14745600;                        // 1,228,800
    float*          b2t   = ws + 15974400;                        // 1,228,800
    unsigned short* an_b  = (unsigned short*)(ws + 17203200);     // 224*208 bf16
    unsigned short* atn_b = (unsigned short*)(ws + 17226496);     // 224*208 bf16
    unsigned short* MeffB = (unsigned short*)(ws + 17249792);     // 9*64*64 bf16
    float*          biasE = ws + 17268224;                        // 64
    float2*         s1p   = (float2*)(ws + 17268288);             // 600 float2
    float2*         s1    = (float2*)(ws + 17269488);             // 8
    float2*         s2p   = (float2*)(ws + 17269504);             // 200
    float2*         s2    = (float2*)(ws + 17269904);             // 8
    float*          xw     = ws + 17269920;                       // 29,491,200
    unsigned short* danr_b = (unsigned short*)(ws + 17269920);    // 768*41600+4992 bf16
    unsigned short* danc_b = danr_b + 31953792;

    k_ln_part<<<dim3(75, 8), dim3(256), 0, stream>>>((const float4*)x, s1p);
    k_ln_final<<<dim3(8), dim3(64), 0, stream>>>(s1p, 75, s1);
    k_xw<<<dim3(2400), dim3(384), 0, stream>>>(x, g1, b1, s1, Wih, bih, xw);
    k_gru<<<dim3(200), dim3(384), 0, stream>>>(xw, x, Whh, bhh, xr, s2p);
    k_ln_final<<<dim3(8), dim3(64), 0, stream>>>(s2p, 25, s2);
    k_tr<<<dim3(200, 6), dim3(256), 0, stream>>>(g2, g2t);
    k_tr<<<dim3(200, 6), dim3(256), 0, stream>>>(b2, b2t);
    k_adjprep<<<dim3(224, 2), dim3(256), 0, stream>>>(adj, an_b, atn_b);
    k_meff<<<dim3(9), dim3(256), 0, stream>>>(Wm, Wg1, Wg2, Wd1, Wd2, bg1, bg2, bd1, bd2, bm, MeffB, biasE);
    k_nx<<<dim3(9600), dim3(256), 0, stream>>>((const float4*)xr, s2, (const float4*)g2t, (const float4*)b2t, nxb);
    k_dprep<<<dim3(768), dim3(256), 0, stream>>>(dyna, danr_b, danc_b);
    k_graph2<<<dim3(768), dim3(512), 0, stream>>>(nxb, xr, an_b, atn_b, danr_b, danc_b, MeffB, biasE, out);
}

// Round 4
// 533.848 us; speedup vs baseline: 6.2843x; 1.5041x over previous
//
#include <hip/hip_runtime.h>
#include <math.h>

#define ALPHA_ 0.1f
#define BETA_  0.9f
#define EPS_   1e-5f

typedef __bf16 bf16x8 __attribute__((ext_vector_type(8)));
typedef float f32x16 __attribute__((ext_vector_type(16)));

__device__ __forceinline__ unsigned short f2bf(float f) {
    return __builtin_bit_cast(unsigned short, (__bf16)f);
}
__device__ __forceinline__ float bf2f(unsigned short u) {
    return (float)__builtin_bit_cast(__bf16, u);
}

__device__ __forceinline__ float wave_reduce_sum(float v) {
#pragma unroll
    for (int off = 32; off > 0; off >>= 1) v += __shfl_down(v, off, 64);
    return v;
}

// ---------------- LN partial sums (per-b mean/var, stage 1) ----------------
__global__ void k_ln_part(const float4* __restrict__ x4, float2* __restrict__ part) {
    const int b = blockIdx.y, jb = blockIdx.x, t = threadIdx.x;
    const size_t base = (size_t)b * 307200 + (size_t)jb * 4096;
    float s = 0.f, sq = 0.f;
#pragma unroll
    for (int k = 0; k < 16; k++) {
        float4 v = x4[base + k * 256 + t];
        s  += v.x + v.y + v.z + v.w;
        sq += v.x * v.x + v.y * v.y + v.z * v.z + v.w * v.w;
    }
    float rs = wave_reduce_sum(s);
    float rq = wave_reduce_sum(sq);
    __shared__ float2 ws[4];
    if ((t & 63) == 0) ws[t >> 6] = make_float2(rs, rq);
    __syncthreads();
    if (t == 0) {
        float a = 0.f, q = 0.f;
        for (int k = 0; k < 4; k++) { a += ws[k].x; q += ws[k].y; }
        part[b * 75 + jb] = make_float2(a, q);
    }
}

__global__ void k_ln_final(const float2* __restrict__ part, int nper, float2* __restrict__ outp) {
    const int b = blockIdx.x, t = threadIdx.x;
    float s = 0.f, sq = 0.f;
    for (int p = t; p < nper; p += 64) {
        float2 v = part[b * nper + p];
        s += v.x; sq += v.y;
    }
    s  = wave_reduce_sum(s);
    sq = wave_reduce_sum(sq);
    if (t == 0) {
        const float invN = 1.f / 1228800.f;
        float mu  = s * invN;
        float var = sq * invN - mu * mu;
        outp[b] = make_float2(mu, rsqrtf(var + EPS_));
    }
}

// ---------------- xw = LN1(x) @ Wih^T + bih  (MFMA bf16) ----------------
// grid 1200 (128 rows each), 256 threads = 4 waves
__global__ __launch_bounds__(256) void k_xw2(const float* __restrict__ x,
        const float* __restrict__ g1, const float* __restrict__ b1,
        const float2* __restrict__ s1, const float* __restrict__ Wih,
        const float* __restrict__ bih, float* __restrict__ xw) {
    __shared__ unsigned short sXb[128 * 64];   // [row][c] bf16, XOR-swizzled
    __shared__ unsigned short sWb[192 * 64];   // [j][k] bf16, XOR-swizzled
    const int t = threadIdx.x;
    const int R0 = blockIdx.x * 128;
    const float2 st1 = s1[R0 / 19200];   // 19200 % 128 == 0: tile within one b
    for (int idx = t; idx < 8192; idx += 256) {
        int rr = idx >> 6, cc = idx & 63;
        int row = R0 + rr;
        int gi = (row % 19200) * 64 + cc;
        float v = (x[(size_t)row * 64 + cc] - st1.x) * st1.y * g1[gi] + b1[gi];
        *(unsigned short*)((char*)sXb + ((rr * 128 + cc * 2) ^ ((rr & 7) << 4))) = f2bf(v);
    }
    for (int idx = t; idx < 12288; idx += 256) {
        int j = idx >> 6, k = idx & 63;
        *(unsigned short*)((char*)sWb + ((j * 128 + k * 2) ^ ((j & 7) << 4))) = f2bf(Wih[idx]);
    }
    __syncthreads();
    const int wid = t >> 6, lane = t & 63, ln = lane & 31, hl = lane >> 5;
    f32x16 acc[6] = {};
#pragma unroll
    for (int ks = 0; ks < 4; ks++) {
        int ao = ((wid * 32 + ln) * 128 + ks * 32 + hl * 16) ^ ((ln & 7) << 4);
        bf16x8 af = __builtin_bit_cast(bf16x8, *(const uint4*)((const char*)sXb + ao));
#pragma unroll
        for (int nt = 0; nt < 6; nt++) {
            int bo = ((nt * 32 + ln) * 128 + ks * 32 + hl * 16) ^ ((ln & 7) << 4);
            bf16x8 bfr = __builtin_bit_cast(bf16x8, *(const uint4*)((const char*)sWb + bo));
            acc[nt] = __builtin_amdgcn_mfma_f32_32x32x16_bf16(af, bfr, acc[nt], 0, 0, 0);
        }
    }
#pragma unroll
    for (int nt = 0; nt < 6; nt++) {
        float bi = bih[nt * 32 + ln];
#pragma unroll
        for (int reg = 0; reg < 16; reg++) {
            int rrow = (reg & 3) + 8 * (reg >> 2) + 4 * hl;
            int row = R0 + wid * 32 + rrow;
            xw[(size_t)row * 192 + nt * 32 + ln] = acc[nt][reg] + bi;
        }
    }
}

// ---------------- persistent GRU, MFMA recurrence, weights in registers ----------------
// 200 blocks x 8 sequences, 512 threads = 8 waves (waves 0..5 do the matvec)
__global__ __launch_bounds__(512) void k_gru2(const float* __restrict__ xw,
        const float* __restrict__ x, const float* __restrict__ Whh,
        const float* __restrict__ bhh, float* __restrict__ xr, float2* __restrict__ s2p) {
    __shared__ unsigned short hb[2048];      // [32][64] bf16, XOR-swizzled; rows 8..31 = 0
    __shared__ float gh[1536];               // [8][192]
    __shared__ float2 sRed[8];
    const int t = threadIdx.x;
    const int wid = t >> 6, lane = t & 63, ln = lane & 31, hl = lane >> 5;
    const int row0 = blockIdx.x * 8;
    const int r = wid;        // gate thread: sequence = wave id
    const int c = t & 63;

    bf16x8 Bf[4];
    if (wid < 6) {
        const int j = wid * 32 + ln;
#pragma unroll
        for (int ks = 0; ks < 4; ks++) {
            const float* wp = Whh + j * 64 + ks * 16 + hl * 8;
            float4 w0 = *(const float4*)wp;
            float4 w1 = *(const float4*)(wp + 4);
            bf16x8 bb;
            bb[0] = (__bf16)w0.x; bb[1] = (__bf16)w0.y; bb[2] = (__bf16)w0.z; bb[3] = (__bf16)w0.w;
            bb[4] = (__bf16)w1.x; bb[5] = (__bf16)w1.y; bb[6] = (__bf16)w1.z; bb[7] = (__bf16)w1.w;
            Bf[ks] = bb;
        }
    }
    for (int i = t; i < 2048; i += 512) hb[i] = 0;

    const float b_r = bhh[c], b_z = bhh[64 + c], b_n = bhh[128 + c];
    const float* xwp = xw + (size_t)(row0 + r) * 96 * 192;
    const float* xp  = x  + (size_t)(row0 + r) * 96 * 64;
    float*       xrp = xr + (size_t)(row0 + r) * 96 * 64;
    float xg = xwp[c], zg = xwp[64 + c], ng = xwp[128 + c];
    float xv = xp[c];
    float h = 0.f, lsum = 0.f, lsq = 0.f;
    __syncthreads();

    for (int st = 0; st < 96; st++) {
        // ---- matvec GH = H8 @ WhhT on MFMA (waves 0..5) ----
        if (wid < 6) {
            f32x16 acc = {};
#pragma unroll
            for (int ks = 0; ks < 4; ks++) {
                int ao = (ln * 128 + ks * 32 + hl * 16) ^ ((ln & 7) << 4);
                bf16x8 af = __builtin_bit_cast(bf16x8, *(const uint4*)((const char*)hb + ao));
                acc = __builtin_amdgcn_mfma_f32_32x32x16_bf16(af, Bf[ks], acc, 0, 0, 0);
            }
#pragma unroll
            for (int reg = 0; reg < 4; reg++) {   // rows 0..7 only (reg&3)+4*hl
                gh[(reg + 4 * hl) * 192 + wid * 32 + ln] = acc[reg];
            }
        }
        __syncthreads();
        // ---- gates: 1 element per thread, h in register ----
        float hr_ = gh[r * 192 + c] + b_r;
        float hz  = gh[r * 192 + 64 + c] + b_z;
        float hn  = gh[r * 192 + 128 + c] + b_n;
        float rg_ = 1.f / (1.f + __expf(-(xg + hr_)));
        float zg_ = 1.f / (1.f + __expf(-(zg + hz)));
        float ny = ng + rg_ * hn;
        ny = fminf(fmaxf(ny, -15.f), 15.f);
        float e2 = __expf(-2.f * ny);
        float nv = (1.f - e2) / (1.f + e2);
        h = nv + zg_ * (h - nv);
        float ov = h + xv;
        xrp[st * 64 + c] = ov;
        lsum += ov; lsq += ov * ov;
        *(unsigned short*)((char*)hb + ((r * 128 + c * 2) ^ ((r & 7) << 4))) = f2bf(h);
        // prefetch next step's xw/x under the next matvec
        int sn = st < 95 ? st + 1 : 95;
        xg = xwp[sn * 192 + c]; zg = xwp[sn * 192 + 64 + c]; ng = xwp[sn * 192 + 128 + c];
        xv = xp[sn * 64 + c];
        __syncthreads();
    }
    float s = wave_reduce_sum(lsum);
    float q = wave_reduce_sum(lsq);
    if (lane == 0) sRed[wid] = make_float2(s, q);
    __syncthreads();
    if (t == 0) {
        float a = 0.f, b_ = 0.f;
        for (int k = 0; k < 8; k++) { a += sRed[k].x; b_ += sRed[k].y; }
        s2p[blockIdx.x] = make_float2(a, b_);
    }
}

// ---------------- transpose g2/b2: [64][200][96] -> [96][200][64] ----------------
__global__ void k_tr(const float* __restrict__ in, float* __restrict__ outp) {
    __shared__ float tile[32][33];
    const int v = blockIdx.x;
    const int ct = blockIdx.y & 1;
    const int lt = blockIdx.y >> 1;
    const int t = threadIdx.x;
    const int lx = t & 31, ly = t >> 5;
    const int c0 = ct * 32, l0 = lt * 32;
#pragma unroll
    for (int q = 0; q < 4; q++) {
        int cc = ly + q * 8;
        tile[cc][lx] = in[(size_t)(c0 + cc) * 19200 + (size_t)v * 96 + l0 + lx];
    }
    __syncthreads();
#pragma unroll
    for (int q = 0; q < 4; q++) {
        int ll = ly + q * 8;
        outp[(size_t)(l0 + ll) * 12800 + (size_t)v * 64 + c0 + lx] = tile[lx][ll];
    }
}

// ---------------- static adjacency -> normalized bf16, padded [224][208] ----------------
__global__ void k_adjprep(const float* __restrict__ adj, unsigned short* __restrict__ an_b,
        unsigned short* __restrict__ atn_b) {
    const int v = blockIdx.x;      // 0..223
    const int mode = blockIdx.y;
    const int t = threadIdx.x;     // 256
    unsigned short* outp = (mode == 0) ? an_b : atn_b;
    if (v >= 200) { if (t < 208) outp[v * 208 + t] = 0; return; }
    float val = 0.f;
    if (t < 200) val = (mode == 0) ? adj[v * 200 + t] : adj[t * 200 + v];
    float s = wave_reduce_sum(val);
    __shared__ float sp[4];
    if ((t & 63) == 0) sp[t >> 6] = s;
    __syncthreads();
    float inv = 1.f / (sp[0] + sp[1] + sp[2] + sp[3] + 1.f);
    if (t < 208) {
        float o = (t < 200) ? (val + (t == v ? 1.f : 0.f)) * inv : 0.f;
        outp[v * 208 + t] = f2bf(o);
    }
}

// ---------------- dyna graph -> normalized bf16 danr/danc, per-(b,l) [200][208] ----------------
__global__ __launch_bounds__(256) void k_dprep(const float* __restrict__ dyna,
        unsigned short* __restrict__ danr, unsigned short* __restrict__ danc) {
    __shared__ float sS[40000];
    __shared__ float sinv[400];
    const int blk = blockIdx.x;
    const int t = threadIdx.x;
    const float* S = dyna + (size_t)blk * 40000;
    for (int idx = t; idx < 40000; idx += 256) sS[idx] = S[idx];
    __syncthreads();
    if (t < 200) {
        float rs = 0.f, cs = 0.f;
        for (int w = 0; w < 200; w++) { rs += sS[t * 200 + w]; cs += sS[w * 200 + t]; }
        sinv[t] = 1.f / (rs + 1.f);
        sinv[200 + t] = 1.f / (cs + 1.f);
    }
    __syncthreads();
    unsigned short* dr = danr + (size_t)blk * 41600;
    unsigned short* dc = danc + (size_t)blk * 41600;
    for (int v = 0; v < 200; v++) {
        if (t < 208) {
            float vr = 0.f, vc = 0.f;
            if (t < 200) {
                float d = (t == v) ? 1.f : 0.f;
                vr = (sS[v * 200 + t] + d) * sinv[v];
                vc = (sS[t * 200 + v] + d) * sinv[200 + v];
            }
            dr[v * 208 + t] = f2bf(vr);
            dc[v * 208 + t] = f2bf(vc);
        }
    }
    if (blk == 767) {
        for (int idx = t; idx < 4992; idx += 256) {
            danr[(size_t)768 * 41600 + idx] = 0;
            danc[(size_t)768 * 41600 + idx] = 0;
        }
    }
}

// ---------------- effective projection matrices -> bf16 MeffB[9][64][64] + biasE ----------------
__global__ void k_meff(const float* __restrict__ Wm, const float* __restrict__ Wg1,
        const float* __restrict__ Wg2, const float* __restrict__ Wd1, const float* __restrict__ Wd2,
        const float* __restrict__ bg1, const float* __restrict__ bg2, const float* __restrict__ bd1,
        const float* __restrict__ bd2, const float* __restrict__ bm,
        unsigned short* __restrict__ MeffB, float* __restrict__ biasE) {
    const int k = blockIdx.x;
    const int t = threadIdx.x;
    const int o = t >> 2;
    const int cb = (t & 3) * 16;
    float acc[16];
#pragma unroll
    for (int q = 0; q < 16; q++) acc[q] = 0.f;
    if (k == 0) {
        for (int m = 0; m < 64; m++) {
            float aL = Wm[o * 128 + m], aR = Wm[o * 128 + 64 + m];
#pragma unroll
            for (int q = 0; q < 16; q++) {
                int cc = cb + q;
                acc[q] += aL * (Wg1[m * 192 + cc] + Wg2[m * 192 + cc])
                        + aR * (Wd1[m * 192 + cc] + Wd2[m * 192 + cc]);
            }
        }
    } else {
        const float* Ws = (k <= 2) ? Wg1 : (k <= 4) ? Wg2 : (k <= 6) ? Wd1 : Wd2;
        const int side = (k <= 4) ? 0 : 64;
        const int hop = (((k - 1) & 1) == 0) ? 64 : 128;
        for (int m = 0; m < 64; m++) {
            float a_ = Wm[o * 128 + side + m];
#pragma unroll
            for (int q = 0; q < 16; q++) acc[q] += a_ * Ws[m * 192 + hop + cb + q];
        }
    }
#pragma unroll
    for (int q = 0; q < 16; q++) MeffB[k * 4096 + o * 64 + cb + q] = f2bf(acc[q]);
    if (k == 0 && t < 64) {
        float s = bm[t];
        for (int cc = 0; cc < 64; cc++)
            s += Wm[t * 128 + cc] * (bg1[cc] + bg2[cc]) + Wm[t * 128 + 64 + cc] * (bd1[cc] + bd2[cc]);
        biasE[t] = s;
    }
}

// ---------------- nx (bf16) = LN2(xr), layout [b*96+l][v][c] ----------------
__global__ void k_nx(const float4* __restrict__ xr4, const float2* __restrict__ s2,
        const float4* __restrict__ g2t4, const float4* __restrict__ b2t4,
        unsigned short* __restrict__ nxb) {
    size_t id = (size_t)blockIdx.x * 256 + threadIdx.x;  // < 2457600
    int cf = (int)(id & 15);
    size_t grp = id >> 4;
    int v = (int)(grp % 200);
    size_t bl = grp / 200;
    int l = (int)(bl % 96);
    int b = (int)(bl / 96);
    float2 st = s2[b];
    float4 xv = xr4[(((size_t)(b * 200 + v)) * 96 + l) * 16 + cf];
    size_t gi = ((size_t)l * 200 + v) * 16 + cf;
    float4 g = g2t4[gi];
    float4 bb = b2t4[gi];
    unsigned int lo = (unsigned)f2bf((xv.x - st.x) * st.y * g.x + bb.x)
                    | ((unsigned)f2bf((xv.y - st.x) * st.y * g.y + bb.y) << 16);
    unsigned int hi = (unsigned)f2bf((xv.z - st.x) * st.y * g.z + bb.z)
                    | ((unsigned)f2bf((xv.w - st.x) * st.y * g.w + bb.w) << 16);
    ((uint2*)nxb)[id] = make_uint2(lo, hi);
}

// ================= MFMA graph kernel =================
#define OFF_HT0 0
#define OFF_H0R 32768
#define OFF_HT1 61440
#define OFF_H1R 94208
#define OFF_H2R 122880
#define OFF_OBUF 61440
#define SMEM_SZ 151552

__device__ __forceinline__ int ht_addr(int c, int w) {
    return (c * 512 + w * 2) ^ (((c >> 2) & 7) << 4);
}
__device__ __forceinline__ int hr_addr(int v, int c) {
    return (v * 128 + c * 2) ^ ((v & 7) << 4);
}

__device__ __forceinline__ void prop_store(unsigned char* smem, const f32x16& acc, int mt, int ct,
        int ln, int half, int dstHt, int dstHr) {
    const int c = ct * 32 + ln;
#pragma unroll
    for (int g = 0; g < 4; g++) {
        const int vb = mt * 32 + half * 4 + g * 8;
        if (vb < 200) {
            unsigned short pk[4];
#pragma unroll
            for (int i = 0; i < 4; i++) {
                const int v = vb + i;
                float h0 = bf2f(*(const unsigned short*)(smem + OFF_H0R + hr_addr(v, c)));
                float hn = ALPHA_ * h0 + BETA_ * acc[g * 4 + i];
                unsigned short bv = f2bf(hn);
                pk[i] = bv;
                *(unsigned short*)(smem + dstHr + hr_addr(v, c)) = bv;
            }
            if (dstHt >= 0) {
                *(uint2*)(smem + dstHt + ht_addr(c, vb)) = make_uint2(
                    (unsigned)pk[0] | ((unsigned)pk[1] << 16),
                    (unsigned)pk[2] | ((unsigned)pk[3] << 16));
            }
        }
    }
}

__device__ __forceinline__ void prop_full(unsigned char* smem, const unsigned short* __restrict__ A,
        int srcHt, int dstHt, int dstHr, int wid, int ln, int half) {
    const int ct = wid & 1;
    const int mt0 = wid >> 1;
    const bool has2 = (wid < 6);
    const int c = ct * 32 + ln;
    f32x16 acc0 = {}; f32x16 acc1 = {};
    const unsigned short* A0p = A + (size_t)(mt0 * 32 + ln) * 208;
    const unsigned short* A1p = A + (size_t)((mt0 + 4) * 32 + ln) * 208;
#pragma unroll
    for (int kk = 0; kk < 13; kk++) {
        const int k0 = kk * 16 + half * 8;
        bf16x8 bf = __builtin_bit_cast(bf16x8, *(const uint4*)(smem + srcHt + ht_addr(c, k0)));
        bf16x8 a0 = __builtin_bit_cast(bf16x8, *(const uint4*)(const void*)(A0p + k0));
        acc0 = __builtin_amdgcn_mfma_f32_32x32x16_bf16(a0, bf, acc0, 0, 0, 0);
        if (has2) {
            bf16x8 a1 = __builtin_bit_cast(bf16x8, *(const uint4*)(const void*)(A1p + k0));
            acc1 = __builtin_amdgcn_mfma_f32_32x32x16_bf16(a1, bf, acc1, 0, 0, 0);
        }
    }
    prop_store(smem, acc0, mt0, ct, ln, half, dstHt, dstHr);
    if (has2) prop_store(smem, acc1, mt0 + 4, ct, ln, half, dstHt, dstHr);
}

__device__ __forceinline__ void proj_step(unsigned char* smem, const unsigned short* __restrict__ MB,
        int srcHr, int wid, int ln, int half, f32x16& A0, f32x16& A1) {
    const int mtO = wid & 1;
    const int nt0 = wid >> 1;
    const bool has2 = (wid < 6);
    const int o = mtO * 32 + ln;
    const int va = nt0 * 32 + ln;
    const int vb = (nt0 + 4) * 32 + ln;
#pragma unroll
    for (int kk = 0; kk < 4; kk++) {
        const int c0 = kk * 16 + half * 8;
        bf16x8 mf = __builtin_bit_cast(bf16x8, *(const uint4*)(const void*)(MB + o * 64 + c0));
        bf16x8 h0 = __builtin_bit_cast(bf16x8, *(const uint4*)(smem + srcHr + hr_addr(va, c0)));
        A0 = __builtin_amdgcn_mfma_f32_32x32x16_bf16(mf, h0, A0, 0, 0, 0);
        if (has2) {
            bf16x8 h1 = __builtin_bit_cast(bf16x8, *(const uint4*)(smem + srcHr + hr_addr(vb, c0)));
            A1 = __builtin_amdgcn_mfma_f32_32x32x16_bf16(mf, h1, A1, 0, 0, 0);
        }
    }
}

__device__ __forceinline__ void store_obuf(unsigned char* smem, const f32x16& acc, int mtO, int ntV,
        int ln, int half) {
    const int v = ntV * 32 + ln;
    if (v >= 200) return;
#pragma unroll
    for (int r = 0; r < 16; r++) {
        const int o = mtO * 32 + half * 4 + (r & 3) + (r >> 2) * 8;
        *(float*)(smem + OFF_OBUF + (o * 200 + v) * 4) = acc[r];
    }
}

__global__ __launch_bounds__(512, 2) void k_graph2(const unsigned short* __restrict__ nxb,
        const float* __restrict__ xrb, const unsigned short* __restrict__ an_b,
        const unsigned short* __restrict__ atn_b, const unsigned short* __restrict__ danr_b,
        const unsigned short* __restrict__ danc_b, const unsigned short* __restrict__ MeffB,
        const float* __restrict__ biasE, float* __restrict__ out) {
    __shared__ __align__(16) unsigned char smem[SMEM_SZ];
    const int blk = blockIdx.x;
    const int b = blk / 96, l = blk % 96;
    const int t = threadIdx.x;
    const int wid = t >> 6, lane = t & 63, ln = lane & 31, half = lane >> 5;

    const unsigned int* nxs = (const unsigned int*)(nxb + (size_t)blk * 12800);
    for (int idx = t; idx < 6400; idx += 512) {
        unsigned int val = nxs[idx];
        int v = idx >> 5, c2 = (idx & 31) * 2;
        *(unsigned int*)(smem + OFF_H0R + hr_addr(v, c2)) = val;
        *(unsigned short*)(smem + OFF_HT0 + ht_addr(c2, v)) = (unsigned short)(val & 0xffffu);
        *(unsigned short*)(smem + OFF_HT0 + ht_addr(c2 + 1, v)) = (unsigned short)(val >> 16);
    }
    for (int idx = t; idx < 768; idx += 512) {
        int v = 200 + (idx >> 5), c2 = (idx & 31) * 2;
        *(unsigned int*)(smem + OFF_H0R + hr_addr(v, c2)) = 0;
    }
    if (t < 512) {
        int c = t >> 3, w = 200 + (t & 7);
        *(unsigned short*)(smem + OFF_HT0 + ht_addr(c, w)) = 0;
        *(unsigned short*)(smem + OFF_HT1 + ht_addr(c, w)) = 0;
    }
    __syncthreads();

    f32x16 ACC0 = {}; f32x16 ACC1 = {};
    proj_step(smem, MeffB, OFF_H0R, wid, ln, half, ACC0, ACC1);

#pragma unroll 1
    for (int chain = 0; chain < 4; chain++) {
        const unsigned short* A = (chain == 0) ? an_b : (chain == 1) ? atn_b
            : (chain == 2) ? (danr_b + (size_t)blk * 41600) : (danc_b + (size_t)blk * 41600);
        prop_full(smem, A, OFF_HT0, OFF_HT1, OFF_H1R, wid, ln, half);
        __syncthreads();
        proj_step(smem, MeffB + (size_t)(1 + 2 * chain) * 4096, OFF_H1R, wid, ln, half, ACC0, ACC1);
        prop_full(smem, A, OFF_HT1, -1, OFF_H2R, wid, ln, half);
        __syncthreads();
        proj_step(smem, MeffB + (size_t)(2 + 2 * chain) * 4096, OFF_H2R, wid, ln, half, ACC0, ACC1);
    }

    {
        const int mtO = wid & 1, nt0 = wid >> 1;
        store_obuf(smem, ACC0, mtO, nt0, ln, half);
        if (wid < 6) store_obuf(smem, ACC1, mtO, nt0 + 4, ln, half);
    }
    __syncthreads();

    const size_t gbase = ((size_t)b * 200 * 96 + l) * 64;
    for (int idx = t; idx < 12800; idx += 512) {
        int v = idx >> 6, o = idx & 63;
        float val = *(const float*)(smem + OFF_OBUF + (o * 200 + v) * 4) + biasE[o];
        size_t gi = gbase + (size_t)v * 6144 + o;
        out[gi] = val + xrb[gi];
    }
}

extern "C" void kernel_launch(void* const* d_in, const int* in_sizes, int n_in,
                              void* d_out, int out_size, void* d_ws, size_t ws_size,
                              hipStream_t stream) {
    (void)in_sizes; (void)n_in; (void)out_size; (void)ws_size;
    const float* x    = (const float*)d_in[0];
    const float* adj  = (const float*)d_in[1];
    const float* dyna = (const float*)d_in[2];
    const float* g1   = (const float*)d_in[3];
    const float* b1   = (const float*)d_in[4];
    const float* g2   = (const float*)d_in[5];
    const float* b2   = (const float*)d_in[6];
    const float* Wih  = (const float*)d_in[7];
    const float* Whh  = (const float*)d_in[8];
    const float* bih  = (const float*)d_in[9];
    const float* bhh  = (const float*)d_in[10];
    const float* Wg1  = (const float*)d_in[11];
    const float* bg1  = (const float*)d_in[12];
    const float* Wg2  = (const float*)d_in[13];
    const float* bg2  = (const float*)d_in[14];
    const float* Wd1  = (const float*)d_in[15];
    const float* bd1  = (const float*)d_in[16];
    const float* Wd2  = (const float*)d_in[17];
    const float* bd2  = (const float*)d_in[18];
    const float* Wm   = (const float*)d_in[19];
    const float* bm   = (const float*)d_in[20];
    float* out = (float*)d_out;
    float* ws = (float*)d_ws;

    float*          xr    = ws;                                   // 9,830,400
    unsigned short* nxb   = (unsigned short*)(ws + 9830400);      // 9,830,400 bf16
    float*          g2t   = ws + 14745600;                        // 1,228,800
    float*          b2t   = ws + 15974400;                        // 1,228,800
    unsigned short* an_b  = (unsigned short*)(ws + 17203200);     // 224*208 bf16
    unsigned short* atn_b = (unsigned short*)(ws + 17226496);     // 224*208 bf16
    unsigned short* MeffB = (unsigned short*)(ws + 17249792);     // 9*64*64 bf16
    float*          biasE = ws + 17268224;                        // 64
    float2*         s1p   = (float2*)(ws + 17268288);             // 600 float2
    float2*         s1    = (float2*)(ws + 17269488);             // 8
    float2*         s2p   = (float2*)(ws + 17269504);             // 200
    float2*         s2    = (float2*)(ws + 17269904);             // 8
    float*          xw     = ws + 17269920;                       // 29,491,200
    unsigned short* danr_b = (unsigned short*)(ws + 17269920);    // 768*41600+4992 bf16
    unsigned short* danc_b = danr_b + 31953792;

    k_ln_part<<<dim3(75, 8), dim3(256), 0, stream>>>((const float4*)x, s1p);
    k_ln_final<<<dim3(8), dim3(64), 0, stream>>>(s1p, 75, s1);
    k_xw2<<<dim3(1200), dim3(256), 0, stream>>>(x, g1, b1, s1, Wih, bih, xw);
    k_gru2<<<dim3(200), dim3(512), 0, stream>>>(xw, x, Whh, bhh, xr, s2p);
    k_ln_final<<<dim3(8), dim3(64), 0, stream>>>(s2p, 25, s2);
    k_tr<<<dim3(200, 6), dim3(256), 0, stream>>>(g2, g2t);
    k_tr<<<dim3(200, 6), dim3(256), 0, stream>>>(b2, b2t);
    k_adjprep<<<dim3(224, 2), dim3(256), 0, stream>>>(adj, an_b, atn_b);
    k_meff<<<dim3(9), dim3(256), 0, stream>>>(Wm, Wg1, Wg2, Wd1, Wd2, bg1, bg2, bd1, bd2, bm, MeffB, biasE);
    k_nx<<<dim3(9600), dim3(256), 0, stream>>>((const float4*)xr, s2, (const float4*)g2t, (const float4*)b2t, nxb);
    k_dprep<<<dim3(768), dim3(256), 0, stream>>>(dyna, danr_b, danc_b);
    k_graph2<<<dim3(768), dim3(512), 0, stream>>>(nxb, xr, an_b, atn_b, danr_b, danc_b, MeffB, biasE, out);
}